// Round 1
// baseline (400.880 us; speedup 1.0000x reference)
//
#include <hip/hip_runtime.h>

#define GH 2048
#define GW 2048
#define OH 2046
#define OW 2046

constexpr int TILE = 32;
constexpr int HALO = 34;   // TILE + 2

__global__ void init_ws(double* ws) {
    if (threadIdx.x < 8) ws[threadIdx.x] = 0.0;
}

__global__ __launch_bounds__(256)
void reduce_E(const float* __restrict__ E, double* ws, int n) {
    int idx = blockIdx.x * blockDim.x + threadIdx.x;
    int stride = gridDim.x * blockDim.x;
    float s = 0.f;
    for (int i = idx; i < n; i += stride) s += E[i];
    #pragma unroll
    for (int off = 32; off > 0; off >>= 1) s += __shfl_down(s, off, 64);
    if ((threadIdx.x & 63) == 0) atomicAdd(&ws[1], (double)s);
}

__global__ __launch_bounds__(256)
void stencil_kernel(const float* __restrict__ E, const float* __restrict__ v,
                    const float* __restrict__ strain, double* ws) {
    __shared__ float sE [HALO][HALO + 1];
    __shared__ float sxx[HALO][HALO + 1];
    __shared__ float syy[HALO][HALO + 1];
    __shared__ float sxy[HALO][HALO + 1];

    const int tileX = blockIdx.x * TILE;
    const int tileY = blockIdx.y * TILE;
    const int t = threadIdx.y * 32 + threadIdx.x;

    // Stage halo tile: compute stress once per staged point.
    for (int p = t; p < HALO * HALO; p += 256) {
        int ly = p / HALO, lx = p - ly * HALO;
        int gi = tileY + ly, gj = tileX + lx;
        float e = 0.f, sx = 0.f, sy = 0.f, sz = 0.f;
        if (gi < GH && gj < GW) {
            int idx = gi * GW + gj;
            e = E[idx];
            float vv  = v[idx];
            float exx = strain[idx * 3 + 0];
            float eyy = strain[idx * 3 + 1];
            float exy = strain[idx * 3 + 2];
            float frac = e / (1.f - vv * vv);
            sx = (exx + vv * eyy) * frac;
            sy = (vv * exx + eyy) * frac;
            sz = exy * (1.f - vv) * 0.5f * frac;
        }
        sE [ly][lx] = e;
        sxx[ly][lx] = sx;
        syy[ly][lx] = sy;
        sxy[ly][lx] = sz;
    }
    __syncthreads();

    float acc = 0.f;
    for (int r = threadIdx.y; r < TILE; r += 8) {
        int oi = tileY + r, oj = tileX + threadIdx.x;
        if (oi < OH && oj < OW) {
            int y = r, x = threadIdx.x;
            float Ec = 0.f;
            #pragma unroll
            for (int di = 0; di < 3; ++di)
                #pragma unroll
                for (int dj = 0; dj < 3; ++dj)
                    Ec += sE[y + di][x + dj];
            // fx = conv(s_xx, [[-1,-1,-1],[0,0,0],[1,1,1]]) + conv(s_xy, [[1,0,-1]x3])
            float fx = (sxx[y + 2][x] + sxx[y + 2][x + 1] + sxx[y + 2][x + 2])
                     - (sxx[y    ][x] + sxx[y    ][x + 1] + sxx[y    ][x + 2])
                     + (sxy[y][x]     + sxy[y + 1][x]     + sxy[y + 2][x])
                     - (sxy[y][x + 2] + sxy[y + 1][x + 2] + sxy[y + 2][x + 2]);
            // fy = conv(s_yy, [[1,0,-1]x3]) + conv(s_xy, [[-1,-1,-1],[0,0,0],[1,1,1]])
            float fy = (syy[y][x]     + syy[y + 1][x]     + syy[y + 2][x])
                     - (syy[y][x + 2] + syy[y + 1][x + 2] + syy[y + 2][x + 2])
                     + (sxy[y + 2][x] + sxy[y + 2][x + 1] + sxy[y + 2][x + 2])
                     - (sxy[y    ][x] + sxy[y    ][x + 1] + sxy[y    ][x + 2]);
            float inv = 1.f / Ec;
            acc += fabsf(fx * inv) + fabsf(fy * inv);
        }
    }
    #pragma unroll
    for (int off = 32; off > 0; off >>= 1) acc += __shfl_down(acc, off, 64);
    if ((t & 63) == 0) atomicAdd(&ws[0], (double)acc);
}

__global__ void finalize_kernel(const double* ws, float* out) {
    double M = (double)OH * (double)OW;
    double loss_xy = ws[0] / M;
    double loss_e = fabs(ws[1] / ((double)GH * (double)GW) - 1.0) / 100.0;
    out[0] = (float)(loss_xy + loss_e);
}

extern "C" void kernel_launch(void* const* d_in, const int* in_sizes, int n_in,
                              void* d_out, int out_size, void* d_ws, size_t ws_size,
                              hipStream_t stream) {
    const float* E      = (const float*)d_in[0];
    const float* v      = (const float*)d_in[1];
    const float* strain = (const float*)d_in[2];
    float* out = (float*)d_out;
    double* ws = (double*)d_ws;

    hipLaunchKernelGGL(init_ws, dim3(1), dim3(64), 0, stream, ws);
    hipLaunchKernelGGL(reduce_E, dim3(2048), dim3(256), 0, stream, E, ws, GH * GW);
    hipLaunchKernelGGL(stencil_kernel, dim3((OW + TILE - 1) / TILE, (OH + TILE - 1) / TILE),
                       dim3(32, 8), 0, stream, E, v, strain, ws);
    hipLaunchKernelGGL(finalize_kernel, dim3(1), dim3(1), 0, stream, ws, out);
}

// Round 2
// 118.782 us; speedup vs baseline: 3.3749x; 3.3749x over previous
//
#include <hip/hip_runtime.h>

#define GH 2048
#define GW 2048
#define OH 2046
#define OW 2046

constexpr int TILE = 32;
constexpr int HALO = 34;   // TILE + 2
constexpr int GRID_X = 64; // 2046/32 rounded up; 64*32 = 2048 covers grid exactly
constexpr int GRID_Y = 64;
constexpr int NBLOCKS = GRID_X * GRID_Y;

__global__ __launch_bounds__(256)
void stencil_kernel(const float* __restrict__ E, const float* __restrict__ v,
                    const float* __restrict__ strain, float2* __restrict__ partials) {
    __shared__ float sE [HALO][HALO + 1];
    __shared__ float sxx[HALO][HALO + 1];
    __shared__ float syy[HALO][HALO + 1];
    __shared__ float sxy[HALO][HALO + 1];
    __shared__ float wsum[4][2];   // per-wave partials {acc, esum}

    const int tileX = blockIdx.x * TILE;
    const int tileY = blockIdx.y * TILE;
    const int t = threadIdx.y * 32 + threadIdx.x;

    // Stage halo tile: compute stress once per staged point.
    for (int p = t; p < HALO * HALO; p += 256) {
        int ly = p / HALO, lx = p - ly * HALO;
        int gi = tileY + ly, gj = tileX + lx;
        float e = 0.f, sx = 0.f, sy = 0.f, sz = 0.f;
        if (gi < GH && gj < GW) {
            int idx = gi * GW + gj;
            e = E[idx];
            float vv  = v[idx];
            float exx = strain[idx * 3 + 0];
            float eyy = strain[idx * 3 + 1];
            float exy = strain[idx * 3 + 2];
            float frac = e / (1.f - vv * vv);
            sx = (exx + vv * eyy) * frac;
            sy = (vv * exx + eyy) * frac;
            sz = exy * (1.f - vv) * 0.5f * frac;
        }
        sE [ly][lx] = e;
        sxx[ly][lx] = sx;
        syy[ly][lx] = sy;
        sxy[ly][lx] = sz;
    }
    __syncthreads();

    float acc = 0.f;
    float eacc = 0.f;
    for (int r = threadIdx.y; r < TILE; r += 8) {
        int y = r, x = threadIdx.x;
        // E-mean contribution: interior 32x32 covers the 2048^2 grid exactly once.
        eacc += sE[y][x];
        int oi = tileY + r, oj = tileX + threadIdx.x;
        if (oi < OH && oj < OW) {
            float Ec = 0.f;
            #pragma unroll
            for (int di = 0; di < 3; ++di)
                #pragma unroll
                for (int dj = 0; dj < 3; ++dj)
                    Ec += sE[y + di][x + dj];
            float fx = (sxx[y + 2][x] + sxx[y + 2][x + 1] + sxx[y + 2][x + 2])
                     - (sxx[y    ][x] + sxx[y    ][x + 1] + sxx[y    ][x + 2])
                     + (sxy[y][x]     + sxy[y + 1][x]     + sxy[y + 2][x])
                     - (sxy[y][x + 2] + sxy[y + 1][x + 2] + sxy[y + 2][x + 2]);
            float fy = (syy[y][x]     + syy[y + 1][x]     + syy[y + 2][x])
                     - (syy[y][x + 2] + syy[y + 1][x + 2] + syy[y + 2][x + 2])
                     + (sxy[y + 2][x] + sxy[y + 2][x + 1] + sxy[y + 2][x + 2])
                     - (sxy[y    ][x] + sxy[y    ][x + 1] + sxy[y    ][x + 2]);
            float inv = 1.f / Ec;
            acc += fabsf(fx * inv) + fabsf(fy * inv);
        }
    }
    #pragma unroll
    for (int off = 32; off > 0; off >>= 1) {
        acc  += __shfl_down(acc,  off, 64);
        eacc += __shfl_down(eacc, off, 64);
    }
    const int wave = t >> 6;
    if ((t & 63) == 0) { wsum[wave][0] = acc; wsum[wave][1] = eacc; }
    __syncthreads();
    if (t == 0) {
        float a = wsum[0][0] + wsum[1][0] + wsum[2][0] + wsum[3][0];
        float e = wsum[0][1] + wsum[1][1] + wsum[2][1] + wsum[3][1];
        partials[blockIdx.y * GRID_X + blockIdx.x] = make_float2(a, e);
    }
}

__global__ __launch_bounds__(256)
void finalize_kernel(const float2* __restrict__ partials, float* __restrict__ out) {
    __shared__ double sacc[4][2];
    double a = 0.0, e = 0.0;
    for (int i = threadIdx.x; i < NBLOCKS; i += 256) {
        float2 p = partials[i];
        a += (double)p.x;
        e += (double)p.y;
    }
    #pragma unroll
    for (int off = 32; off > 0; off >>= 1) {
        a += __shfl_down(a, off, 64);
        e += __shfl_down(e, off, 64);
    }
    const int wave = threadIdx.x >> 6;
    if ((threadIdx.x & 63) == 0) { sacc[wave][0] = a; sacc[wave][1] = e; }
    __syncthreads();
    if (threadIdx.x == 0) {
        double A = sacc[0][0] + sacc[1][0] + sacc[2][0] + sacc[3][0];
        double Esum = sacc[0][1] + sacc[1][1] + sacc[2][1] + sacc[3][1];
        double M = (double)OH * (double)OW;
        double loss_xy = A / M;
        double loss_e = fabs(Esum / ((double)GH * (double)GW) - 1.0) / 100.0;
        out[0] = (float)(loss_xy + loss_e);
    }
}

extern "C" void kernel_launch(void* const* d_in, const int* in_sizes, int n_in,
                              void* d_out, int out_size, void* d_ws, size_t ws_size,
                              hipStream_t stream) {
    const float* E      = (const float*)d_in[0];
    const float* v      = (const float*)d_in[1];
    const float* strain = (const float*)d_in[2];
    float* out = (float*)d_out;
    float2* partials = (float2*)d_ws;

    hipLaunchKernelGGL(stencil_kernel, dim3(GRID_X, GRID_Y), dim3(32, 8), 0, stream,
                       E, v, strain, partials);
    hipLaunchKernelGGL(finalize_kernel, dim3(1), dim3(256), 0, stream, partials, out);
}